// Round 8
// baseline (1698.996 us; speedup 1.0000x reference)
//
#include <hip/hip_runtime.h>
#include <hip/hip_fp16.h>
#include <cfloat>
#include <type_traits>

#define DEV __device__ __forceinline__

DEV unsigned enc_ord(float f) {
    unsigned u = __float_as_uint(f);
    return (u & 0x80000000u) ? ~u : (u | 0x80000000u);
}

// ================= bucketed CSR build =================
// Buckets of 512 dst nodes (bucket = dst >> 9). Edges are stored grouped by
// (4-row dst group, 16K-src window), each entry packed (src<<2)|rowLocal.
// pp4[group*8 + w] = segment start for window w (w=0..nw-1), slot nw = end.

__global__ __launch_bounds__(256) void k_bcount(const int* __restrict__ dst, int* __restrict__ bcnt, int E) {
    __shared__ int hist[256];
    int tid = threadIdx.x;
    hist[tid] = 0;
    __syncthreads();
    int base = blockIdx.x * 4096;
#pragma unroll
    for (int j = 0; j < 16; ++j) {
        int e = base + j * 256 + tid;
        if (e < E) atomicAdd(&hist[dst[e] >> 9], 1);
    }
    __syncthreads();
    if (hist[tid]) atomicAdd(&bcnt[tid], hist[tid]);
}

__global__ __launch_bounds__(256) void k_bscan(const int* __restrict__ bcnt, int* __restrict__ bbase,
                                               int* __restrict__ bcur, int nb, int E) {
    __shared__ int sh[256];
    int tid = threadIdx.x;
    int v = (tid < nb) ? bcnt[tid] : 0;
    sh[tid] = v; __syncthreads();
    for (int off = 1; off < 256; off <<= 1) {
        int x = (tid >= off) ? sh[tid - off] : 0; __syncthreads();
        sh[tid] += x; __syncthreads();
    }
    int excl = sh[tid] - v;
    if (tid < nb) { bbase[tid] = excl; bcur[tid] = excl; }
    if (tid == 0) bbase[nb] = E;
}

__global__ __launch_bounds__(256) void k_bscatter(const int* __restrict__ ei, int* __restrict__ bcur,
                                                  int2* __restrict__ pairs, int E) {
    __shared__ int hist[256];
    __shared__ int gbase[256];
    int tid = threadIdx.x;
    hist[tid] = 0;
    __syncthreads();
    int base = blockIdx.x * 4096;
    int d[16], li[16];
#pragma unroll
    for (int j = 0; j < 16; ++j) {
        int e = base + j * 256 + tid;
        if (e < E) {
            d[j] = ei[E + e];
            li[j] = atomicAdd(&hist[d[j] >> 9], 1);
        }
    }
    __syncthreads();
    if (hist[tid]) gbase[tid] = atomicAdd(&bcur[tid], hist[tid]);
    __syncthreads();
#pragma unroll
    for (int j = 0; j < 16; ++j) {
        int e = base + j * 256 + tid;
        if (e < E) {
            int b = d[j] >> 9;
            pairs[gbase[b] + li[j]] = make_int2(ei[e], d[j]);
        }
    }
}

// per-bucket: (group,window) LDS histogram -> scan -> pp4/dinv, tagged fill of colT
__global__ __launch_bounds__(512) void k_bfill(const int2* __restrict__ pairs, const int* __restrict__ bbase,
                                               float* __restrict__ dinv, int* __restrict__ colT,
                                               int* __restrict__ pp4, int n) {
    __shared__ int hist[1024];    // [group(128)][window slot(8)]; reused as cursors
    __shared__ int degRow[512];
    __shared__ int ssum[512];
    int tid = threadIdx.x;
    int b = blockIdx.x;
    int bb = bbase[b], be = bbase[b + 1];
    int nodeBase = b << 9;
    hist[tid] = 0; hist[tid + 512] = 0; degRow[tid] = 0;
    __syncthreads();
    for (int e = bb + tid; e < be; e += 512) {
        int2 pr = pairs[e];
        int dl = pr.y & 511;
        int w = pr.x >> 14;              // 16K-node src window
        atomicAdd(&hist[(dl >> 2) * 8 + w], 1);
        atomicAdd(&degRow[dl], 1);
    }
    __syncthreads();
    int s0 = hist[2 * tid], s1 = hist[2 * tid + 1];
    int tsum = s0 + s1;
    ssum[tid] = tsum; __syncthreads();
    for (int off = 1; off < 512; off <<= 1) {
        int x = (tid >= off) ? ssum[tid - off] : 0; __syncthreads();
        ssum[tid] += x; __syncthreads();
    }
    int excl = ssum[tid] - tsum;
    __syncthreads();
    hist[2 * tid] = excl;                // cursors (pre-fill values)
    hist[2 * tid + 1] = excl + s0;
    // pp4 global index identity: gg*8+w == nodeBase*2 + slot
    pp4[nodeBase * 2 + 2 * tid] = bb + excl;
    pp4[nodeBase * 2 + 2 * tid + 1] = bb + excl + s0;
    int node = nodeBase + tid;
    if (node < n) dinv[node] = rsqrtf((float)degRow[tid] + 1.0f);  // +1 self loop
    __syncthreads();
    for (int e = bb + tid; e < be; e += 512) {
        int2 pr = pairs[e];
        int dl = pr.y & 511;
        int w = pr.x >> 14;
        int p = atomicAdd(&hist[(dl >> 2) * 8 + w], 1);
        colT[bb + p] = (pr.x << 2) | (dl & 3);   // packed (src, rowLocal)
    }
}

// ================= dense matmul =================
// out[r,c] = (dinv[r]?) * sum_k in[r,k]*W[k,c] (+bias); fp32 compute, TIN/TOUT storage
template <int K, int COUT, bool SCALE, bool BIAS, typename TIN, typename TOUT>
__global__ __launch_bounds__(256) void k_mm(const TIN* __restrict__ in, const float* __restrict__ W,
                                            const float* __restrict__ bias, const float* __restrict__ dinv,
                                            TOUT* __restrict__ out, int n, int ldw, int ldo, int colOff) {
    constexpr int CG = COUT / 4;
    constexpr int SLOTS = 256 / CG;
    constexpr int TR = (K == 128) ? 32 : 64;
    constexpr int RPT = TR / SLOTS;
    constexpr int KP = K + 1;
    __shared__ __align__(16) float sW[K * COUT];
    __shared__ float sH[TR * KP];
    const int tid = threadIdx.x;
    const int rowBase = blockIdx.x * TR;

    constexpr int W4 = COUT / 4;
    for (int idx = tid; idx < K * W4; idx += 256) {
        int k = idx / W4, c4 = idx - k * W4;
        ((float4*)sW)[idx] = *(const float4*)(W + (size_t)k * ldw + colOff + c4 * 4);
    }
    if constexpr (std::is_same<TIN, float>::value) {
        const float4* inp4 = (const float4*)(in + (size_t)rowBase * K);
        for (int idx = tid; idx < TR * K / 4; idx += 256) {
            int elem = idx * 4;
            int r = elem / K, k = elem - r * K;
            float4 h = (rowBase + r < n) ? inp4[idx] : make_float4(0.f, 0.f, 0.f, 0.f);
            float* dd = &sH[r * KP + k];
            dd[0] = h.x; dd[1] = h.y; dd[2] = h.z; dd[3] = h.w;
        }
    } else {
        const uint4* inp8 = (const uint4*)(in + (size_t)rowBase * K);
        for (int idx = tid; idx < TR * K / 8; idx += 256) {
            int elem = idx * 8;
            int r = elem / K, k = elem - r * K;
            uint4 h = make_uint4(0u, 0u, 0u, 0u);
            if (rowBase + r < n) h = inp8[idx];
            const __half2* hh = (const __half2*)&h;
            float* dd = &sH[r * KP + k];
#pragma unroll
            for (int q = 0; q < 4; ++q) {
                float2 f = __half22float2(hh[q]);
                dd[2 * q] = f.x; dd[2 * q + 1] = f.y;
            }
        }
    }
    __syncthreads();

    const int cg = tid % CG;
    const int slot = tid / CG;
    float4 acc[RPT];
#pragma unroll
    for (int j = 0; j < RPT; ++j) acc[j] = make_float4(0.f, 0.f, 0.f, 0.f);
#pragma unroll 4
    for (int k = 0; k < K; ++k) {
        float4 w = *(const float4*)&sW[k * COUT + cg * 4];
#pragma unroll
        for (int j = 0; j < RPT; ++j) {
            float h = sH[(slot + j * SLOTS) * KP + k];
            acc[j].x += h * w.x; acc[j].y += h * w.y; acc[j].z += h * w.z; acc[j].w += h * w.w;
        }
    }
#pragma unroll
    for (int j = 0; j < RPT; ++j) {
        int r = rowBase + slot + j * SLOTS;
        if (r < n) {
            float4 o = acc[j];
            if (SCALE) { float di = dinv[r]; o.x *= di; o.y *= di; o.z *= di; o.w *= di; }
            if (BIAS) {
                float4 b = *(const float4*)(bias + colOff + cg * 4);
                o.x += b.x; o.y += b.y; o.z += b.z; o.w += b.w;
            }
            if constexpr (std::is_same<TOUT, float>::value) {
                *(float4*)(out + (size_t)r * ldo + colOff + cg * 4) = o;
            } else {
                __half2 p0 = __floats2half2_rn(o.x, o.y);
                __half2 p1 = __floats2half2_rn(o.z, o.w);
                uint2 st;
                st.x = *(unsigned*)&p0; st.y = *(unsigned*)&p1;
                *(uint2*)(out + (size_t)r * ldo + colOff + cg * 4) = st;
            }
        }
    }
}

// ================= phased aggregation, dense tagged streams =================
// Each LPR-lane segment owns a 4-row group (acc[4][8] registers) and streams
// its dense (group,window) edge list: packed (src<<2)|rowLocal entries, no
// per-row loops. Tag-predicated FMAs route each edge to its accumulator row.
// Per-window __syncthreads keeps the block's waves window-aligned; a fully
// co-resident grid keeps blocks aligned (perf heuristic only — correctness
// never depends on cross-block timing).
// MODE 0: relu(di*s+b)  1: di*s+b  2: di*relu(di*s+b)  3: di^2*s  4: di*s
template <int LPR, int MODE>
__global__ __launch_bounds__(256, 4) void k_agg(const __half* __restrict__ g, const int* __restrict__ pp4,
                                                const int* __restrict__ colT, const float* __restrict__ dinv,
                                                const float* __restrict__ bias, __half* __restrict__ out,
                                                int n, int nw) {
    constexpr int SEGS = 64 / LPR;    // segments per wave (8 for 64-wide, 4 for 128-wide)
    constexpr int GPB = 4 * SEGS;     // groups per block
    const int tid = threadIdx.x;
    const int wave = tid >> 6, lane = tid & 63;
    const int seg = lane / LPR, sl = lane % LPR;
    const int group = blockIdx.x * GPB + wave * SEGS + seg;
    const int rowBase = group * 4;
    const uint4* g4 = (const uint4*)g + sl;

    float acc[4][8];
#pragma unroll
    for (int j = 0; j < 4; ++j) {     // init with self-loop row
        int row = rowBase + j;
        uint4 s = make_uint4(0u, 0u, 0u, 0u);
        if (row < n) s = g4[(size_t)row * LPR];
        const __half2* h = (const __half2*)&s;
#pragma unroll
        for (int q = 0; q < 4; ++q) {
            float2 f = __half22float2(h[q]);
            acc[j][2 * q] = f.x; acc[j][2 * q + 1] = f.y;
        }
    }

    for (int w = 0; w < nw; ++w) {
        int e0 = 0, e1 = 0;
        if (rowBase < n) {
            e0 = pp4[group * 8 + w];
            e1 = pp4[group * 8 + w + 1];
        }
        for (int eb = e0; eb < e1; eb += 8) {
            int ct[8];
#pragma unroll
            for (int t = 0; t < 8; ++t) ct[t] = colT[eb + t];   // colT padded by 8
            uint4 v[8];
#pragma unroll
            for (int t = 0; t < 8; ++t) {
                v[t] = make_uint4(0u, 0u, 0u, 0u);
                if (eb + t < e1) v[t] = g4[(size_t)(ct[t] >> 2) * LPR];
            }
#pragma unroll
            for (int t = 0; t < 8; ++t) {
                const __half2* h = (const __half2*)&v[t];
                float f[8];
#pragma unroll
                for (int q = 0; q < 4; ++q) {
                    float2 fq = __half22float2(h[q]);
                    f[2 * q] = fq.x; f[2 * q + 1] = fq.y;
                }
                int tg = ct[t] & 3;
#pragma unroll
                for (int r = 0; r < 4; ++r) {
                    float mr = (tg == r) ? 1.f : 0.f;   // v[t]==0 when masked -> adds 0
#pragma unroll
                    for (int k = 0; k < 8; ++k) acc[r][k] = fmaf(mr, f[k], acc[r][k]);
                }
            }
        }
        __syncthreads();   // window-phase alignment (no data dependence)
    }

#pragma unroll
    for (int j = 0; j < 4; ++j) {
        int row = rowBase + j;
        if (row >= n) continue;
        float di = dinv[row];
        float r8[8];
        if (MODE <= 2) {
            float4 b0 = *(const float4*)(bias + sl * 8);
            float4 b1 = *(const float4*)(bias + sl * 8 + 4);
            float bb[8] = {b0.x, b0.y, b0.z, b0.w, b1.x, b1.y, b1.z, b1.w};
#pragma unroll
            for (int t = 0; t < 8; ++t) {
                float s = di * acc[j][t] + bb[t];
                if (MODE == 0) r8[t] = fmaxf(s, 0.f);
                else if (MODE == 1) r8[t] = s;
                else r8[t] = di * fmaxf(s, 0.f);
            }
        } else if (MODE == 3) {
            float d2 = di * di;
#pragma unroll
            for (int t = 0; t < 8; ++t) r8[t] = acc[j][t] * d2;
        } else {
#pragma unroll
            for (int t = 0; t < 8; ++t) r8[t] = acc[j][t] * di;
        }
        uint4 o;
        __half2* oh = (__half2*)&o;
#pragma unroll
        for (int q = 0; q < 4; ++q) oh[q] = __floats2half2_rn(r8[2 * q], r8[2 * q + 1]);
        *((uint4*)out + (size_t)row * LPR + sl) = o;
    }
}

// ================= global max pool (batch sorted) =================
__global__ __launch_bounds__(64) void k_pool(const float* __restrict__ z, const int* __restrict__ batch,
                                             unsigned* __restrict__ pooled, int n) {
    constexpr int ROWS = 128;
    int lane = threadIdx.x;
    int r0 = blockIdx.x * ROWS;
    if (r0 >= n) return;
    int r1 = min(r0 + ROWS, n);
    int cur = batch[r0];
    float m = -FLT_MAX;
    for (int r = r0; r < r1; ++r) {
        int b = batch[r];
        float v = z[(size_t)r * 64 + lane];
        if (b != cur) {
            atomicMax(&pooled[cur * 64 + lane], enc_ord(m));
            cur = b; m = v;
        } else {
            m = fmaxf(m, v);
        }
    }
    atomicMax(&pooled[cur * 64 + lane], enc_ord(m));
}

// ================= final MLP =================
__global__ __launch_bounds__(256) void k_mlp(const unsigned* __restrict__ pooled,
                                             const float* __restrict__ fc1w, const float* __restrict__ fc1b,
                                             const float* __restrict__ fc2w, const float* __restrict__ fc2b,
                                             const float* __restrict__ cpdw, const float* __restrict__ cpdb,
                                             const float* __restrict__ combw, const float* __restrict__ combb,
                                             float* __restrict__ out, int G) {
    __shared__ float s1[64 * 32], s2[32 * 16], sb1[32], sb2[16], scw[16], sow[16], shead[2];
    int tid = threadIdx.x;
    for (int i = tid; i < 2048; i += 256) s1[i] = fc1w[i];
    for (int i = tid; i < 512; i += 256) s2[i] = fc2w[i];
    if (tid < 32) sb1[tid] = fc1b[tid];
    if (tid < 16) { sb2[tid] = fc2b[tid]; scw[tid] = cpdw[tid]; sow[tid] = combw[tid]; }
    if (tid == 0) { shead[0] = cpdb[0]; shead[1] = combb[0]; }
    __syncthreads();
    if (tid < G) {
        float h0[64];
#pragma unroll
        for (int k = 0; k < 64; ++k) {
            unsigned u = pooled[tid * 64 + k];
            unsigned b = (u & 0x80000000u) ? (u & 0x7fffffffu) : ~u;
            h0[k] = __uint_as_float(b);
        }
        float h1[32];
#pragma unroll
        for (int j = 0; j < 32; ++j) {
            float a = sb1[j];
#pragma unroll
            for (int k = 0; k < 64; ++k) a += h0[k] * s1[k * 32 + j];
            h1[j] = fmaxf(a, 0.f);
        }
        float h2[16];
#pragma unroll
        for (int j = 0; j < 16; ++j) {
            float a = sb2[j];
#pragma unroll
            for (int k = 0; k < 32; ++k) a += h1[k] * s2[k * 16 + j];
            h2[j] = fmaxf(a, 0.f);
        }
        float c1 = shead[0], c2 = shead[1];
#pragma unroll
        for (int k = 0; k < 16; ++k) { c1 += h2[k] * scw[k]; c2 += h2[k] * sow[k]; }
        out[tid] = c1;
        out[G + tid] = c2;
    }
}

extern "C" void kernel_launch(void* const* d_in, const int* in_sizes, int n_in,
                              void* d_out, int out_size, void* d_ws, size_t ws_size,
                              hipStream_t stream) {
    const float* x      = (const float*)d_in[0];
    const int*   ei     = (const int*)d_in[1];
    const int*   batch  = (const int*)d_in[2];
    const float* enc_w1 = (const float*)d_in[3];
    const float* enc_b1 = (const float*)d_in[4];
    const float* enc_w2 = (const float*)d_in[5];
    const float* enc_b2 = (const float*)d_in[6];
    const float* w1 = (const float*)d_in[7];   const float* b1 = (const float*)d_in[8];
    const float* w2 = (const float*)d_in[9];   const float* b2 = (const float*)d_in[10];
    const float* w3 = (const float*)d_in[11];  const float* b3 = (const float*)d_in[12];
    const float* sgw = (const float*)d_in[13]; const float* sgb = (const float*)d_in[14];
    const float* fc1w = (const float*)d_in[15]; const float* fc1b = (const float*)d_in[16];
    const float* fc2w = (const float*)d_in[17]; const float* fc2b = (const float*)d_in[18];
    const float* cpdw = (const float*)d_in[19]; const float* cpdb = (const float*)d_in[20];
    const float* combw = (const float*)d_in[21]; const float* combb = (const float*)d_in[22];

    const int n = in_sizes[0] / 128;
    const int E = in_sizes[1] / 2;
    const int G = out_size / 2;
    const int nb = (n + 511) >> 9;           // dst buckets
    const int nw = ((n - 1) >> 14) + 1;      // 16K-src-node windows (7 for n=100000)
    float* outp = (float*)d_out;

    char* p = (char*)d_ws;
    auto alloc = [&](size_t bytes) -> char* {
        char* r = p;
        p += (bytes + 255) & ~(size_t)255;
        return r;
    };
    float* dinv      = (float*)alloc((size_t)n * 4);
    int* bcnt        = (int*)alloc(256 * 4);
    int* bbase       = (int*)alloc(257 * 4);
    int* bcur        = (int*)alloc(256 * 4);
    int* colT        = (int*)alloc(((size_t)E + 8) * 4);      // +8 pad for batch over-read
    int* pp4         = (int*)alloc((size_t)nb * 1024 * 4);    // per-(4-row group) window ptrs
    unsigned* pooled = (unsigned*)alloc((size_t)G * 64 * 4);
    __half* A        = (__half*)alloc((size_t)n * 128 * 4);   // oversized: aliases pairs (E*8 B)
    __half* B        = (__half*)alloc((size_t)n * 128 * 2);
    float* Cf        = (float*)alloc((size_t)n * 64 * 4);
    int2* pairs      = (int2*)A;  // alias: pairs dead before first k_mm writes A

    hipMemsetAsync(bcnt, 0, 256 * 4, stream);
    hipMemsetAsync(pooled, 0, (size_t)G * 64 * 4, stream);

    const int gE = (E + 4095) / 4096;
    k_bcount<<<gE, 256, 0, stream>>>(ei + E, bcnt, E);
    k_bscan<<<1, 256, 0, stream>>>(bcnt, bbase, bcur, nb, E);
    k_bscatter<<<gE, 256, 0, stream>>>(ei, bcur, pairs, E);
    k_bfill<<<nb, 512, 0, stream>>>(pairs, bbase, dinv, colT, pp4, n);

    const int gm128 = (n + 31) / 32;
    const int gm64  = (n + 63) / 64;
    const int ga64  = (n + 127) / 128;    // 32 groups/block = 128 rows (782 blocks, co-resident)
    const int ga128 = (n + 63) / 64;      // 16 groups/block = 64 rows

    // encoder layer 1: x fp32 -> A fp16 (two column halves), propagate+relu (128-wide)
    k_mm<128, 64, true, false, float, __half><<<gm128, 256, 0, stream>>>(x, enc_w1, nullptr, dinv, A, n, 128, 128, 0);
    k_mm<128, 64, true, false, float, __half><<<gm128, 256, 0, stream>>>(x, enc_w1, nullptr, dinv, A, n, 128, 128, 64);
    k_agg<16, 0><<<ga128, 256, 0, stream>>>(A, pp4, colT, dinv, enc_b1, B, n, nw);
    // encoder layer 2: [N,128] fp16 -> [N,64] fp16
    k_mm<128, 64, true, false, __half, __half><<<gm128, 256, 0, stream>>>(B, enc_w2, nullptr, dinv, A, n, 64, 64, 0);
    k_agg<8, 1><<<ga64, 256, 0, stream>>>(A, pp4, colT, dinv, enc_b2, B, n, nw);
    // conv1, conv2
    k_mm<64, 64, true, false, __half, __half><<<gm64, 256, 0, stream>>>(B, w1, nullptr, dinv, A, n, 64, 64, 0);
    k_agg<8, 0><<<ga64, 256, 0, stream>>>(A, pp4, colT, dinv, b1, B, n, nw);
    k_mm<64, 64, true, false, __half, __half><<<gm64, 256, 0, stream>>>(B, w2, nullptr, dinv, A, n, 64, 64, 0);
    k_agg<8, 0><<<ga64, 256, 0, stream>>>(A, pp4, colT, dinv, b2, B, n, nw);
    // conv3 (output pre-scaled by dinv for SG chain)
    k_mm<64, 64, true, false, __half, __half><<<gm64, 256, 0, stream>>>(B, w3, nullptr, dinv, A, n, 64, 64, 0);
    k_agg<8, 2><<<ga64, 256, 0, stream>>>(A, pp4, colT, dinv, b3, B, n, nw);
    // SGConv K=4 propagates
    k_agg<8, 3><<<ga64, 256, 0, stream>>>(B, pp4, colT, dinv, b3, A, n, nw);
    k_agg<8, 3><<<ga64, 256, 0, stream>>>(A, pp4, colT, dinv, b3, B, n, nw);
    k_agg<8, 3><<<ga64, 256, 0, stream>>>(B, pp4, colT, dinv, b3, A, n, nw);
    k_agg<8, 4><<<ga64, 256, 0, stream>>>(A, pp4, colT, dinv, b3, B, n, nw);
    // SG linear -> fp32 for pool
    k_mm<64, 64, false, true, __half, float><<<gm64, 256, 0, stream>>>(B, sgw, sgb, dinv, Cf, n, 64, 64, 0);
    // pool + heads
    k_pool<<<(n + 127) / 128, 64, 0, stream>>>(Cf, batch, pooled, n);
    k_mlp<<<1, 256, 0, stream>>>(pooled, fc1w, fc1b, fc2w, fc2b, cpdw, cpdb, combw, combb, outp, G);
}

// Round 9
// 1327.576 us; speedup vs baseline: 1.2798x; 1.2798x over previous
//
#include <hip/hip_runtime.h>
#include <hip/hip_fp16.h>
#include <cfloat>
#include <type_traits>

#define DEV __device__ __forceinline__

DEV unsigned enc_ord(float f) {
    unsigned u = __float_as_uint(f);
    return (u & 0x80000000u) ? ~u : (u | 0x80000000u);
}

// ================= bucketed CSR build =================
// Buckets of 512 dst nodes (bucket = dst >> 9); per-row edges sorted by src
// window (window = src >> 14, 16K nodes = 2MB fp16-64; nw = ceil(n/16384) <= 7).
// pp[row*8 + w] = start of window-w segment; pp[row*8 + nw] = row end.

__global__ __launch_bounds__(256) void k_bcount(const int* __restrict__ dst, int* __restrict__ bcnt, int E) {
    __shared__ int hist[256];
    int tid = threadIdx.x;
    hist[tid] = 0;
    __syncthreads();
    int base = blockIdx.x * 4096;
#pragma unroll
    for (int j = 0; j < 16; ++j) {
        int e = base + j * 256 + tid;
        if (e < E) atomicAdd(&hist[dst[e] >> 9], 1);
    }
    __syncthreads();
    if (hist[tid]) atomicAdd(&bcnt[tid], hist[tid]);
}

__global__ __launch_bounds__(256) void k_bscan(const int* __restrict__ bcnt, int* __restrict__ bbase,
                                               int* __restrict__ bcur, int nb, int E) {
    __shared__ int sh[256];
    int tid = threadIdx.x;
    int v = (tid < nb) ? bcnt[tid] : 0;
    sh[tid] = v; __syncthreads();
    for (int off = 1; off < 256; off <<= 1) {
        int x = (tid >= off) ? sh[tid - off] : 0; __syncthreads();
        sh[tid] += x; __syncthreads();
    }
    int excl = sh[tid] - v;
    if (tid < nb) { bbase[tid] = excl; bcur[tid] = excl; }
    if (tid == 0) bbase[nb] = E;
}

__global__ __launch_bounds__(256) void k_bscatter(const int* __restrict__ ei, int* __restrict__ bcur,
                                                  int2* __restrict__ pairs, int E) {
    __shared__ int hist[256];
    __shared__ int gbase[256];
    int tid = threadIdx.x;
    hist[tid] = 0;
    __syncthreads();
    int base = blockIdx.x * 4096;
    int d[16], li[16];
#pragma unroll
    for (int j = 0; j < 16; ++j) {
        int e = base + j * 256 + tid;
        if (e < E) {
            d[j] = ei[E + e];
            li[j] = atomicAdd(&hist[d[j] >> 9], 1);
        }
    }
    __syncthreads();
    if (hist[tid]) gbase[tid] = atomicAdd(&bcur[tid], hist[tid]);
    __syncthreads();
#pragma unroll
    for (int j = 0; j < 16; ++j) {
        int e = base + j * 256 + tid;
        if (e < E) {
            int b = d[j] >> 9;
            pairs[gbase[b] + li[j]] = make_int2(ei[e], d[j]);
        }
    }
}

// per-bucket: (node,window) LDS histogram -> scan -> pp/dinv, window-sorted colA fill
__global__ __launch_bounds__(512) void k_bfill(const int2* __restrict__ pairs, const int* __restrict__ bbase,
                                               float* __restrict__ dinv, int* __restrict__ colA,
                                               int* __restrict__ pp, int n, int nw) {
    __shared__ int sdeg2[512 * 8];   // 16 KB; reused as cursors after scan
    __shared__ int ssum[512];
    int tid = threadIdx.x;
    int b = blockIdx.x;
    int bb = bbase[b], be = bbase[b + 1];
    int nodeBase = b << 9;
    for (int i = tid; i < 512 * 8; i += 512) sdeg2[i] = 0;
    __syncthreads();
    for (int e = bb + tid; e < be; e += 512) {
        int2 pr = pairs[e];
        atomicAdd(&sdeg2[(pr.y & 511) * 8 + (pr.x >> 14)], 1);
    }
    __syncthreads();
    int vals[8], ex[8];
    int tsum = 0;
#pragma unroll
    for (int q = 0; q < 8; ++q) {
        vals[q] = (q < nw) ? sdeg2[tid * 8 + q] : 0;
        ex[q] = tsum; tsum += vals[q];
    }
    ssum[tid] = tsum; __syncthreads();
    for (int off = 1; off < 512; off <<= 1) {
        int x = (tid >= off) ? ssum[tid - off] : 0; __syncthreads();
        ssum[tid] += x; __syncthreads();
    }
    int excl = ssum[tid] - tsum;
    __syncthreads();
#pragma unroll
    for (int q = 0; q < 8; ++q) if (q < nw) sdeg2[tid * 8 + q] = excl + ex[q];
    int node = nodeBase + tid;
    if (node < n) {
        dinv[node] = rsqrtf((float)tsum + 1.0f);  // +1 self loop
        for (int q = 0; q < nw; ++q) pp[node * 8 + q] = bb + excl + ex[q];
        pp[node * 8 + nw] = bb + excl + tsum;     // row end
    }
    __syncthreads();
    for (int e = bb + tid; e < be; e += 512) {
        int2 pr = pairs[e];
        int idx = (pr.y & 511) * 8 + (pr.x >> 14);
        int p2 = atomicAdd(&sdeg2[idx], 1);
        colA[bb + p2] = pr.x;
    }
}

// ================= dense matmul =================
// out[r,c] = (dinv[r]?) * sum_k in[r,k]*W[k,c] (+bias); fp32 compute, TIN/TOUT storage
template <int K, int COUT, bool SCALE, bool BIAS, typename TIN, typename TOUT>
__global__ __launch_bounds__(256) void k_mm(const TIN* __restrict__ in, const float* __restrict__ W,
                                            const float* __restrict__ bias, const float* __restrict__ dinv,
                                            TOUT* __restrict__ out, int n, int ldw, int ldo, int colOff) {
    constexpr int CG = COUT / 4;
    constexpr int SLOTS = 256 / CG;
    constexpr int TR = (K == 128) ? 32 : 64;
    constexpr int RPT = TR / SLOTS;
    constexpr int KP = K + 1;
    __shared__ __align__(16) float sW[K * COUT];
    __shared__ float sH[TR * KP];
    const int tid = threadIdx.x;
    const int rowBase = blockIdx.x * TR;

    constexpr int W4 = COUT / 4;
    for (int idx = tid; idx < K * W4; idx += 256) {
        int k = idx / W4, c4 = idx - k * W4;
        ((float4*)sW)[idx] = *(const float4*)(W + (size_t)k * ldw + colOff + c4 * 4);
    }
    if constexpr (std::is_same<TIN, float>::value) {
        const float4* inp4 = (const float4*)(in + (size_t)rowBase * K);
        for (int idx = tid; idx < TR * K / 4; idx += 256) {
            int elem = idx * 4;
            int r = elem / K, k = elem - r * K;
            float4 h = (rowBase + r < n) ? inp4[idx] : make_float4(0.f, 0.f, 0.f, 0.f);
            float* dd = &sH[r * KP + k];
            dd[0] = h.x; dd[1] = h.y; dd[2] = h.z; dd[3] = h.w;
        }
    } else {
        const uint4* inp8 = (const uint4*)(in + (size_t)rowBase * K);
        for (int idx = tid; idx < TR * K / 8; idx += 256) {
            int elem = idx * 8;
            int r = elem / K, k = elem - r * K;
            uint4 h = make_uint4(0u, 0u, 0u, 0u);
            if (rowBase + r < n) h = inp8[idx];
            const __half2* hh = (const __half2*)&h;
            float* dd = &sH[r * KP + k];
#pragma unroll
            for (int q = 0; q < 4; ++q) {
                float2 f = __half22float2(hh[q]);
                dd[2 * q] = f.x; dd[2 * q + 1] = f.y;
            }
        }
    }
    __syncthreads();

    const int cg = tid % CG;
    const int slot = tid / CG;
    float4 acc[RPT];
#pragma unroll
    for (int j = 0; j < RPT; ++j) acc[j] = make_float4(0.f, 0.f, 0.f, 0.f);
#pragma unroll 4
    for (int k = 0; k < K; ++k) {
        float4 w = *(const float4*)&sW[k * COUT + cg * 4];
#pragma unroll
        for (int j = 0; j < RPT; ++j) {
            float h = sH[(slot + j * SLOTS) * KP + k];
            acc[j].x += h * w.x; acc[j].y += h * w.y; acc[j].z += h * w.z; acc[j].w += h * w.w;
        }
    }
#pragma unroll
    for (int j = 0; j < RPT; ++j) {
        int r = rowBase + slot + j * SLOTS;
        if (r < n) {
            float4 o = acc[j];
            if (SCALE) { float di = dinv[r]; o.x *= di; o.y *= di; o.z *= di; o.w *= di; }
            if (BIAS) {
                float4 b = *(const float4*)(bias + colOff + cg * 4);
                o.x += b.x; o.y += b.y; o.z += b.z; o.w += b.w;
            }
            if constexpr (std::is_same<TOUT, float>::value) {
                *(float4*)(out + (size_t)r * ldo + colOff + cg * 4) = o;
            } else {
                __half2 p0 = __floats2half2_rn(o.x, o.y);
                __half2 p1 = __floats2half2_rn(o.z, o.w);
                uint2 st;
                st.x = *(unsigned*)&p0; st.y = *(unsigned*)&p1;
                *(uint2*)(out + (size_t)r * ldo + colOff + cg * 4) = st;
            }
        }
    }
}

// ================= 128-wide simple streaming aggregation (enc1) =================
// r4-proven structure: 16-lane segments, 1 row/segment, 8-deep pipelined gathers.
template <int MODE>
__global__ __launch_bounds__(256) void k_aggs(const __half* __restrict__ g, const int* __restrict__ pp,
                                              const int* __restrict__ col, const float* __restrict__ dinv,
                                              const float* __restrict__ bias, __half* __restrict__ out,
                                              int n, int nw) {
    constexpr int LPR = 16;
    constexpr int RPW = 4;
    int gw = (blockIdx.x * 256 + threadIdx.x) >> 6;
    int lane = threadIdx.x & 63;
    int seg = lane / LPR, sl = lane % LPR;
    int row = gw * RPW + seg;
    if (row >= n) return;
    const uint4* g4 = (const uint4*)g + sl;
    float acc[8];
    {
        uint4 s = g4[(size_t)row * LPR];  // self loop
        const __half2* h = (const __half2*)&s;
#pragma unroll
        for (int q = 0; q < 4; ++q) {
            float2 f = __half22float2(h[q]);
            acc[2 * q] = f.x; acc[2 * q + 1] = f.y;
        }
    }
    int e0 = pp[row * 8], e1 = pp[row * 8 + nw];
    if (e0 < e1) {
        const int e1m1 = e1 - 1;
        int c[8];
#pragma unroll
        for (int j = 0; j < 8; ++j) c[j] = col[min(e0 + j, e1m1)];
        for (int eb = e0; eb < e1; eb += 8) {
            uint4 v[8];
#pragma unroll
            for (int j = 0; j < 8; ++j) {
                v[j] = make_uint4(0u, 0u, 0u, 0u);
                if (eb + j < e1) v[j] = g4[(size_t)c[j] * LPR];
            }
            int cn[8];
#pragma unroll
            for (int j = 0; j < 8; ++j) cn[j] = col[min(eb + 8 + j, e1m1)];
#pragma unroll
            for (int j = 0; j < 8; ++j) {
                const __half2* h = (const __half2*)&v[j];
#pragma unroll
                for (int q = 0; q < 4; ++q) {
                    float2 f = __half22float2(h[q]);
                    acc[2 * q] += f.x;
                    acc[2 * q + 1] += f.y;
                }
            }
#pragma unroll
            for (int j = 0; j < 8; ++j) c[j] = cn[j];
        }
    }
    float di = dinv[row];
    float r8[8];
    float4 b0 = *(const float4*)(bias + sl * 8);
    float4 b1 = *(const float4*)(bias + sl * 8 + 4);
    float bb[8] = {b0.x, b0.y, b0.z, b0.w, b1.x, b1.y, b1.z, b1.w};
#pragma unroll
    for (int t = 0; t < 8; ++t) {
        float s = di * acc[t] + bb[t];
        r8[t] = (MODE == 0) ? fmaxf(s, 0.f) : s;
    }
    uint4 o;
    __half2* oh = (__half2*)&o;
#pragma unroll
    for (int q = 0; q < 4; ++q) oh[q] = __floats2half2_rn(r8[2 * q], r8[2 * q + 1]);
    *((uint4*)out + (size_t)row * LPR + sl) = o;
}

// ================= 64-wide windowed aggregation (register acc + barriers) =================
// Each 8-lane segment owns 4 rows (acc[4][8] registers); block sweeps 16K-node
// src windows in order with a per-window __syncthreads. Grid (782 blocks) is
// fully co-resident at __launch_bounds__(256,4), so all blocks sweep the same
// ~2MB window together -> per-XCD L2 residency. Alignment is a perf heuristic
// only; correctness never depends on cross-block timing.
// MODE 0: relu(di*s+b)  1: di*s+b  2: di*relu(di*s+b)  3: di^2*s  4: di*s
template <int MODE>
__global__ __launch_bounds__(256, 4) void k_aggw(const __half* __restrict__ g, const int* __restrict__ pp,
                                                 const int* __restrict__ col, const float* __restrict__ dinv,
                                                 const float* __restrict__ bias, __half* __restrict__ out,
                                                 int n, int nw) {
    constexpr int LPR = 8;            // 8 lanes x 16B = 64-wide fp16 row
    const int tid = threadIdx.x;
    const int wave = tid >> 6, lane = tid & 63;
    const int seg = lane >> 3, sl = lane & 7;
    const int rowBase = blockIdx.x * 128 + wave * 32 + seg * 4;
    const uint4* g4 = (const uint4*)g + sl;

    float acc[4][8];
#pragma unroll
    for (int j = 0; j < 4; ++j) {     // init with self-loop row
        int row = rowBase + j;
        uint4 s = make_uint4(0u, 0u, 0u, 0u);
        if (row < n) s = g4[(size_t)row * LPR];
        const __half2* h = (const __half2*)&s;
#pragma unroll
        for (int q = 0; q < 4; ++q) {
            float2 f = __half22float2(h[q]);
            acc[j][2 * q] = f.x; acc[j][2 * q + 1] = f.y;
        }
    }

    for (int w = 0; w < nw; ++w) {
#pragma unroll
        for (int j = 0; j < 4; ++j) {
            int row = rowBase + j;
            if (row < n) {
                int e0 = pp[row * 8 + w];
                int e1 = pp[row * 8 + w + 1];
                if (e0 < e1) {
                    const int e1m1 = e1 - 1;
                    for (int eb = e0; eb < e1; eb += 8) {
                        int cc[8];
#pragma unroll
                        for (int t = 0; t < 8; ++t) cc[t] = col[min(eb + t, e1m1)];
                        uint4 v[8];
#pragma unroll
                        for (int t = 0; t < 8; ++t) {
                            v[t] = make_uint4(0u, 0u, 0u, 0u);
                            if (eb + t < e1) v[t] = g4[(size_t)cc[t] * LPR];
                        }
#pragma unroll
                        for (int t = 0; t < 8; ++t) {
                            const __half2* h = (const __half2*)&v[t];
#pragma unroll
                            for (int q = 0; q < 4; ++q) {
                                float2 f = __half22float2(h[q]);
                                acc[j][2 * q] += f.x;
                                acc[j][2 * q + 1] += f.y;
                            }
                        }
                    }
                }
            }
        }
        __syncthreads();   // window-phase alignment (no data dependence)
    }

#pragma unroll
    for (int j = 0; j < 4; ++j) {
        int row = rowBase + j;
        if (row >= n) continue;
        float di = dinv[row];
        float r8[8];
        if (MODE <= 2) {
            float4 b0 = *(const float4*)(bias + sl * 8);
            float4 b1 = *(const float4*)(bias + sl * 8 + 4);
            float bb[8] = {b0.x, b0.y, b0.z, b0.w, b1.x, b1.y, b1.z, b1.w};
#pragma unroll
            for (int t = 0; t < 8; ++t) {
                float s = di * acc[j][t] + bb[t];
                if (MODE == 0) r8[t] = fmaxf(s, 0.f);
                else if (MODE == 1) r8[t] = s;
                else r8[t] = di * fmaxf(s, 0.f);
            }
        } else if (MODE == 3) {
            float d2 = di * di;
#pragma unroll
            for (int t = 0; t < 8; ++t) r8[t] = acc[j][t] * d2;
        } else {
#pragma unroll
            for (int t = 0; t < 8; ++t) r8[t] = acc[j][t] * di;
        }
        uint4 o;
        __half2* oh = (__half2*)&o;
#pragma unroll
        for (int q = 0; q < 4; ++q) oh[q] = __floats2half2_rn(r8[2 * q], r8[2 * q + 1]);
        *((uint4*)out + (size_t)row * LPR + sl) = o;
    }
}

// ================= global max pool (batch sorted) =================
__global__ __launch_bounds__(64) void k_pool(const float* __restrict__ z, const int* __restrict__ batch,
                                             unsigned* __restrict__ pooled, int n) {
    constexpr int ROWS = 128;
    int lane = threadIdx.x;
    int r0 = blockIdx.x * ROWS;
    if (r0 >= n) return;
    int r1 = min(r0 + ROWS, n);
    int cur = batch[r0];
    float m = -FLT_MAX;
    for (int r = r0; r < r1; ++r) {
        int b = batch[r];
        float v = z[(size_t)r * 64 + lane];
        if (b != cur) {
            atomicMax(&pooled[cur * 64 + lane], enc_ord(m));
            cur = b; m = v;
        } else {
            m = fmaxf(m, v);
        }
    }
    atomicMax(&pooled[cur * 64 + lane], enc_ord(m));
}

// ================= final MLP =================
__global__ __launch_bounds__(256) void k_mlp(const unsigned* __restrict__ pooled,
                                             const float* __restrict__ fc1w, const float* __restrict__ fc1b,
                                             const float* __restrict__ fc2w, const float* __restrict__ fc2b,
                                             const float* __restrict__ cpdw, const float* __restrict__ cpdb,
                                             const float* __restrict__ combw, const float* __restrict__ combb,
                                             float* __restrict__ out, int G) {
    __shared__ float s1[64 * 32], s2[32 * 16], sb1[32], sb2[16], scw[16], sow[16], shead[2];
    int tid = threadIdx.x;
    for (int i = tid; i < 2048; i += 256) s1[i] = fc1w[i];
    for (int i = tid; i < 512; i += 256) s2[i] = fc2w[i];
    if (tid < 32) sb1[tid] = fc1b[tid];
    if (tid < 16) { sb2[tid] = fc2b[tid]; scw[tid] = cpdw[tid]; sow[tid] = combw[tid]; }
    if (tid == 0) { shead[0] = cpdb[0]; shead[1] = combb[0]; }
    __syncthreads();
    if (tid < G) {
        float h0[64];
#pragma unroll
        for (int k = 0; k < 64; ++k) {
            unsigned u = pooled[tid * 64 + k];
            unsigned b = (u & 0x80000000u) ? (u & 0x7fffffffu) : ~u;
            h0[k] = __uint_as_float(b);
        }
        float h1[32];
#pragma unroll
        for (int j = 0; j < 32; ++j) {
            float a = sb1[j];
#pragma unroll
            for (int k = 0; k < 64; ++k) a += h0[k] * s1[k * 32 + j];
            h1[j] = fmaxf(a, 0.f);
        }
        float h2[16];
#pragma unroll
        for (int j = 0; j < 16; ++j) {
            float a = sb2[j];
#pragma unroll
            for (int k = 0; k < 32; ++k) a += h1[k] * s2[k * 16 + j];
            h2[j] = fmaxf(a, 0.f);
        }
        float c1 = shead[0], c2 = shead[1];
#pragma unroll
        for (int k = 0; k < 16; ++k) { c1 += h2[k] * scw[k]; c2 += h2[k] * sow[k]; }
        out[tid] = c1;
        out[G + tid] = c2;
    }
}

extern "C" void kernel_launch(void* const* d_in, const int* in_sizes, int n_in,
                              void* d_out, int out_size, void* d_ws, size_t ws_size,
                              hipStream_t stream) {
    const float* x      = (const float*)d_in[0];
    const int*   ei     = (const int*)d_in[1];
    const int*   batch  = (const int*)d_in[2];
    const float* enc_w1 = (const float*)d_in[3];
    const float* enc_b1 = (const float*)d_in[4];
    const float* enc_w2 = (const float*)d_in[5];
    const float* enc_b2 = (const float*)d_in[6];
    const float* w1 = (const float*)d_in[7];   const float* b1 = (const float*)d_in[8];
    const float* w2 = (const float*)d_in[9];   const float* b2 = (const float*)d_in[10];
    const float* w3 = (const float*)d_in[11];  const float* b3 = (const float*)d_in[12];
    const float* sgw = (const float*)d_in[13]; const float* sgb = (const float*)d_in[14];
    const float* fc1w = (const float*)d_in[15]; const float* fc1b = (const float*)d_in[16];
    const float* fc2w = (const float*)d_in[17]; const float* fc2b = (const float*)d_in[18];
    const float* cpdw = (const float*)d_in[19]; const float* cpdb = (const float*)d_in[20];
    const float* combw = (const float*)d_in[21]; const float* combb = (const float*)d_in[22];

    const int n = in_sizes[0] / 128;
    const int E = in_sizes[1] / 2;
    const int G = out_size / 2;
    const int nb = (n + 511) >> 9;           // dst buckets
    const int nw = ((n - 1) >> 14) + 1;      // 16K-src-node windows (7 for n=100000)
    float* outp = (float*)d_out;

    char* p = (char*)d_ws;
    auto alloc = [&](size_t bytes) -> char* {
        char* r = p;
        p += (bytes + 255) & ~(size_t)255;
        return r;
    };
    float* dinv      = (float*)alloc((size_t)n * 4);
    int* bcnt        = (int*)alloc(256 * 4);
    int* bbase       = (int*)alloc(257 * 4);
    int* bcur        = (int*)alloc(256 * 4);
    int* colA        = (int*)alloc((size_t)E * 4);
    int* pp          = (int*)alloc((size_t)n * 8 * 4);   // per-row window pointers
    unsigned* pooled = (unsigned*)alloc((size_t)G * 64 * 4);
    __half* A        = (__half*)alloc((size_t)n * 128 * 4);  // oversized: aliases pairs (E*8 B)
    __half* B        = (__half*)alloc((size_t)n * 128 * 2);
    float* Cf        = (float*)alloc((size_t)n * 64 * 4);
    int2* pairs      = (int2*)A;  // alias: pairs dead before first k_mm writes A

    hipMemsetAsync(bcnt, 0, 256 * 4, stream);
    hipMemsetAsync(pooled, 0, (size_t)G * 64 * 4, stream);

    const int gE = (E + 4095) / 4096;
    k_bcount<<<gE, 256, 0, stream>>>(ei + E, bcnt, E);
    k_bscan<<<1, 256, 0, stream>>>(bcnt, bbase, bcur, nb, E);
    k_bscatter<<<gE, 256, 0, stream>>>(ei, bcur, pairs, E);
    k_bfill<<<nb, 512, 0, stream>>>(pairs, bbase, dinv, colA, pp, n, nw);

    const int gm128 = (n + 31) / 32;
    const int gm64  = (n + 63) / 64;
    const int gaw   = (n + 127) / 128;    // windowed 64-wide: 128 rows/block, 782 co-resident
    const int gas   = (n + 15) / 16;      // simple 128-wide: 16 rows/block

    // encoder layer 1: x fp32 -> A fp16 (two column halves), propagate+relu (128-wide)
    k_mm<128, 64, true, false, float, __half><<<gm128, 256, 0, stream>>>(x, enc_w1, nullptr, dinv, A, n, 128, 128, 0);
    k_mm<128, 64, true, false, float, __half><<<gm128, 256, 0, stream>>>(x, enc_w1, nullptr, dinv, A, n, 128, 128, 64);
    k_aggs<0><<<gas, 256, 0, stream>>>(A, pp, colA, dinv, enc_b1, B, n, nw);
    // encoder layer 2: [N,128] fp16 -> [N,64] fp16
    k_mm<128, 64, true, false, __half, __half><<<gm128, 256, 0, stream>>>(B, enc_w2, nullptr, dinv, A, n, 64, 64, 0);
    k_aggw<1><<<gaw, 256, 0, stream>>>(A, pp, colA, dinv, enc_b2, B, n, nw);
    // conv1, conv2
    k_mm<64, 64, true, false, __half, __half><<<gm64, 256, 0, stream>>>(B, w1, nullptr, dinv, A, n, 64, 64, 0);
    k_aggw<0><<<gaw, 256, 0, stream>>>(A, pp, colA, dinv, b1, B, n, nw);
    k_mm<64, 64, true, false, __half, __half><<<gm64, 256, 0, stream>>>(B, w2, nullptr, dinv, A, n, 64, 64, 0);
    k_aggw<0><<<gaw, 256, 0, stream>>>(A, pp, colA, dinv, b2, B, n, nw);
    // conv3 (output pre-scaled by dinv for SG chain)
    k_mm<64, 64, true, false, __half, __half><<<gm64, 256, 0, stream>>>(B, w3, nullptr, dinv, A, n, 64, 64, 0);
    k_aggw<2><<<gaw, 256, 0, stream>>>(A, pp, colA, dinv, b3, B, n, nw);
    // SGConv K=4 propagates
    k_aggw<3><<<gaw, 256, 0, stream>>>(B, pp, colA, dinv, b3, A, n, nw);
    k_aggw<3><<<gaw, 256, 0, stream>>>(A, pp, colA, dinv, b3, B, n, nw);
    k_aggw<3><<<gaw, 256, 0, stream>>>(B, pp, colA, dinv, b3, A, n, nw);
    k_aggw<4><<<gaw, 256, 0, stream>>>(A, pp, colA, dinv, b3, B, n, nw);
    // SG linear -> fp32 for pool
    k_mm<64, 64, false, true, __half, float><<<gm64, 256, 0, stream>>>(B, sgw, sgb, dinv, Cf, n, 64, 64, 0);
    // pool + heads
    k_pool<<<(n + 127) / 128, 64, 0, stream>>>(Cf, batch, pooled, n);
    k_mlp<<<1, 256, 0, stream>>>(pooled, fc1w, fc1b, fc2w, fc2b, cpdw, cpdb, combw, combb, outp, G);
}